// Round 1
// baseline (232.993 us; speedup 1.0000x reference)
//
#include <hip/hip_runtime.h>

// Problem geometry (fixed per reference):
//   imgsA, recon_A, warped_BA : [2,1,128,128,128] f32  -> VOL = 4,194,304
//   flow_BA                   : [2,3,128,128,128] f32  -> FLOW = 12,582,912
//   outputs: (ncc, mse, smooth) f32 scalars
#define VOL   4194304
#define FLOWN 12582912
#define SMCNT 12484608.0f   // 2*3*127*128*128 (count of each diff array)
#define WIN_INV (1.0f / 729.0f)

// ---------------- block reduction helper ----------------
__device__ __forceinline__ void block_reduce_atomic(float v, float* red, float* dst) {
#pragma unroll
    for (int off = 32; off; off >>= 1) v += __shfl_down(v, off);
    if ((threadIdx.x & 63) == 0) red[threadIdx.x >> 6] = v;
    __syncthreads();
    if (threadIdx.x == 0) atomicAdd(dst, red[0] + red[1] + red[2] + red[3]);
}

// ---------------- pass 1: products + box-sum along W ----------------
// grid: 16384 blocks x 256 threads, 2 rows of 128 per block
__global__ __launch_bounds__(256) void pass1_k(const float* __restrict__ I,
                                               const float* __restrict__ J,
                                               float* __restrict__ s1) {
    __shared__ float sh[2][5][136];   // 4-pad each side
    const int r = threadIdx.x >> 7;   // row within block
    const int w = threadIdx.x & 127;
    const long row  = (long)blockIdx.x * 2 + r;
    const long base = row * 128;

    if (w < 4) {
#pragma unroll
        for (int c = 0; c < 5; ++c) { sh[r][c][w] = 0.f; sh[r][c][132 + w] = 0.f; }
    }
    const float a = I[base + w];
    const float b = J[base + w];
    sh[r][0][w + 4] = a;
    sh[r][1][w + 4] = b;
    sh[r][2][w + 4] = a * a;
    sh[r][3][w + 4] = b * b;
    sh[r][4][w + 4] = a * b;
    __syncthreads();
#pragma unroll
    for (int c = 0; c < 5; ++c) {
        float s = 0.f;
#pragma unroll
        for (int k = 0; k < 9; ++k) s += sh[r][c][w + k];
        s1[(long)c * VOL + base + w] = s;
    }
}

// ---------------- pass 2: box-sum along H, in-place per plane ----------------
// grid: 5*2*128 = 1280 blocks x 256 threads; each block owns one contiguous
// (h,w) plane of 16384 floats, staged entirely in LDS (64 KB) then rewritten.
__global__ __launch_bounds__(256) void pass2_k(float* __restrict__ s1) {
    __shared__ float sh[128][128];
    const long base = (long)blockIdx.x * 16384;
    for (int i = threadIdx.x; i < 16384; i += 256)
        sh[i >> 7][i & 127] = s1[base + i];
    __syncthreads();
    for (int i = threadIdx.x; i < 16384; i += 256) {
        const int h = i >> 7, w = i & 127;
        const int k0 = (h - 4 > 0) ? h - 4 : 0;
        const int k1 = (h + 4 < 127) ? h + 4 : 127;
        float s = 0.f;
        for (int k = k0; k <= k1; ++k) s += sh[k][w];
        s1[base + i] = s;
    }
}

// ---------------- pass 3: box-sum along D + cc + reduce ----------------
// grid: 2*128*8 = 2048 blocks x 256; block = (n, h, w-tile of 16), all 128 d.
__global__ __launch_bounds__(256) void pass3_k(const float* __restrict__ s1,
                                               float* __restrict__ acc) {
    __shared__ float sh[5][136][16];  // 43.5 KB, 4-row zero pad each side
    __shared__ float red[4];
    const int b  = blockIdx.x;
    const int wt = b & 7;
    const int h  = (b >> 3) & 127;
    const int n  = b >> 10;
    const int w0 = wt << 4;

    // zero pads
    for (int i = threadIdx.x; i < 5 * 4 * 16; i += 256) {
        const int c = i / 64, rr = (i >> 4) & 3, w = i & 15;
        sh[c][rr][w] = 0.f;
        sh[c][132 + rr][w] = 0.f;
    }
    // load 5 channels of the (d x 16) strip
    for (int i = threadIdx.x; i < 5 * 128 * 16; i += 256) {
        const int c = i >> 11;
        const int d = (i >> 4) & 127;
        const int w = i & 15;
        sh[c][4 + d][w] =
            s1[(long)c * VOL + ((((long)n * 128 + d) * 128 + h) << 7) + w0 + w];
    }
    __syncthreads();

    float local = 0.f;
    for (int i = threadIdx.x; i < 128 * 16; i += 256) {
        const int d = i >> 4, w = i & 15;
        float Is = 0, Js = 0, I2 = 0, J2 = 0, IJ = 0;
#pragma unroll
        for (int k = 0; k < 9; ++k) {
            Is += sh[0][d + k][w];
            Js += sh[1][d + k][w];
            I2 += sh[2][d + k][w];
            J2 += sh[3][d + k][w];
            IJ += sh[4][d + k][w];
        }
        const float cross = IJ - Is * Js * WIN_INV;
        const float iv    = I2 - Is * Is * WIN_INV;
        const float jv    = J2 - Js * Js * WIN_INV;
        local += cross * cross / (iv * jv + 1e-5f);
    }
    block_reduce_atomic(local, red, &acc[0]);
}

// ---------------- MSE ----------------
__global__ __launch_bounds__(256) void mse_k(const float4* __restrict__ a,
                                             const float4* __restrict__ b,
                                             float* __restrict__ acc) {
    __shared__ float red[4];
    float local = 0.f;
    const int stride = gridDim.x * 256;
    for (int i = blockIdx.x * 256 + threadIdx.x; i < VOL / 4; i += stride) {
        const float4 x = a[i], y = b[i];
        const float d0 = x.x - y.x, d1 = x.y - y.y, d2 = x.z - y.z, d3 = x.w - y.w;
        local += d0 * d0 + d1 * d1 + d2 * d2 + d3 * d3;
    }
    block_reduce_atomic(local, red, &acc[1]);
}

// ---------------- smoothness ----------------
__global__ __launch_bounds__(256) void smooth_k(const float* __restrict__ s,
                                                float* __restrict__ acc) {
    __shared__ float red[4];
    float local = 0.f;
    const int stride = gridDim.x * 256;
    for (int i = blockIdx.x * 256 + threadIdx.x; i < FLOWN; i += stride) {
        const int w = i & 127, h = (i >> 7) & 127, d = (i >> 14) & 127;
        const float v = s[i];
        if (w < 127) { const float t = s[i + 1]     - v; local += t * t; }
        if (h < 127) { const float t = s[i + 128]   - v; local += t * t; }
        if (d < 127) { const float t = s[i + 16384] - v; local += t * t; }
    }
    block_reduce_atomic(local, red, &acc[2]);
}

// ---------------- finalize ----------------
__global__ void fin_k(const float* __restrict__ acc, float* __restrict__ out) {
    if (threadIdx.x == 0) {
        out[0] = 1.0f - acc[0] * (1.0f / (float)VOL);
        out[1] = acc[1] * (1.0f / (float)VOL);
        out[2] = acc[2] * (1.0f / (3.0f * SMCNT));
    }
}

extern "C" void kernel_launch(void* const* d_in, const int* in_sizes, int n_in,
                              void* d_out, int out_size, void* d_ws, size_t ws_size,
                              hipStream_t stream) {
    const float* imgsA  = (const float*)d_in[0];
    const float* recon  = (const float*)d_in[1];
    const float* warped = (const float*)d_in[2];
    const float* flow   = (const float*)d_in[3];
    float* out = (float*)d_out;
    float* acc = (float*)d_ws;
    float* s1  = (float*)((char*)d_ws + 256);   // 5 * VOL floats = 80 MB

    hipMemsetAsync(d_ws, 0, 16, stream);

    // NCC(I = warped_BA, J = imgsA)
    pass1_k<<<16384, 256, 0, stream>>>(warped, imgsA, s1);
    pass2_k<<<1280, 256, 0, stream>>>(s1);
    pass3_k<<<2048, 256, 0, stream>>>(s1, acc);
    mse_k<<<1024, 256, 0, stream>>>((const float4*)imgsA, (const float4*)recon, acc);
    smooth_k<<<2048, 256, 0, stream>>>(flow, acc);
    fin_k<<<1, 64, 0, stream>>>(acc, out);
}

// Round 2
// 134.294 us; speedup vs baseline: 1.7349x; 1.7349x over previous
//
#include <hip/hip_runtime.h>

// Geometry (fixed): imgs [2,1,128,128,128] f32, flow [2,3,128,128,128] f32
#define VOL   4194304
#define FLOWN 12582912
#define SMCNT 12484608.0f   // 2*3*127*128*128
#define WIN_INV (1.0f / 729.0f)

__device__ __forceinline__ void block_reduce_atomic(float v, float* red, float* dst) {
#pragma unroll
    for (int off = 32; off; off >>= 1) v += __shfl_down(v, off);
    if ((threadIdx.x & 63) == 0) red[threadIdx.x >> 6] = v;
    __syncthreads();
    if (threadIdx.x == 0) atomicAdd(dst, red[0] + red[1] + red[2] + red[3]);
}

// ---------------- fused NCC: W-sum + H-sum in LDS, D-window in registers ----
// Block = (n, h-tile 16, w-tile 16, d-chunk 16). Grid = 2*8*8*8 = 1024.
// Marches 24 planes (16 emitted + 4 halo each side), 9-deep register ring
// with static indices via the unroll-by-9 inner loop.
__global__ __launch_bounds__(256) void ncc_k(const float* __restrict__ I,
                                             const float* __restrict__ J,
                                             float* __restrict__ acc) {
    __shared__ __align__(16) float ch[5][24][24];  // channel products, halo region
    __shared__ __align__(16) float ws[5][24][16];  // W-summed, h-halo x 16 w
    __shared__ float red[4];

    const int bid = blockIdx.x;
    const int wt = bid & 7, ht = (bid >> 3) & 7, dc = (bid >> 6) & 7, n = bid >> 9;
    const int w0 = wt << 4, h0 = ht << 4, d0 = dc << 4;
    const int tid = threadIdx.x;
    const int th = tid >> 4, tw = tid & 15;          // owned (h,w) in tile

    float ring[5][9];
#pragma unroll
    for (int c = 0; c < 5; ++c)
#pragma unroll
        for (int u = 0; u < 9; ++u) ring[c][u] = 0.f;
    float S[5] = {0.f, 0.f, 0.f, 0.f, 0.f};
    float local = 0.f;

    const long nbase = (long)n * 2097152;            // n * 128^3

    for (int s9 = 0; s9 < 27; s9 += 9) {             // 27 steps, ring idx = u (static)
#pragma unroll
        for (int u = 0; u < 9; ++u) {
            const int step = s9 + u;
            const int dp = d0 - 4 + step;            // plane being ingested
            float p[5];
            const bool valid = (step < 24) && (dp >= 0) && (dp < 128);
            if (valid) {                             // uniform branch
                const long dbase = nbase + (long)dp * 16384;
                // ---- load halo region, form 5 channels ----
                for (int i = tid; i < 576; i += 256) {
                    const int rr = i / 24, j = i - rr * 24;
                    const int gh = h0 - 4 + rr, gw = w0 - 4 + j;
                    float a = 0.f, b = 0.f;
                    if ((unsigned)gh < 128u && (unsigned)gw < 128u) {
                        const long idx = dbase + gh * 128 + gw;
                        a = I[idx];
                        b = J[idx];
                    }
                    ch[0][rr][j] = a;
                    ch[1][rr][j] = b;
                    ch[2][rr][j] = a * a;
                    ch[3][rr][j] = b * b;
                    ch[4][rr][j] = a * b;
                }
                __syncthreads();
                // ---- W-sum: sliding window, 3x float4 -> 4 outputs ----
                for (int i = tid; i < 480; i += 256) {
                    const int c = i / 96, rem = i - c * 96;
                    const int r = rem >> 2, q = rem & 3;
                    const float4 f0 = *(const float4*)&ch[c][r][4 * q];
                    const float4 f1 = *(const float4*)&ch[c][r][4 * q + 4];
                    const float4 f2 = *(const float4*)&ch[c][r][4 * q + 8];
                    const float o0 = f0.x + f0.y + f0.z + f0.w +
                                     f1.x + f1.y + f1.z + f1.w + f2.x;
                    const float o1 = o0 - f0.x + f2.y;
                    const float o2 = o1 - f0.y + f2.z;
                    const float o3 = o2 - f0.z + f2.w;
                    *(float4*)&ws[c][r][4 * q] = make_float4(o0, o1, o2, o3);
                }
                __syncthreads();
                // ---- H-sum at owned position (2-way bank alias = free) ----
#pragma unroll
                for (int c = 0; c < 5; ++c) {
                    float s = 0.f;
#pragma unroll
                    for (int k = 0; k < 9; ++k) s += ws[c][th + k][tw];
                    p[c] = s;
                }
                __syncthreads();                      // protect ch/ws for next plane
            } else {
#pragma unroll
                for (int c = 0; c < 5; ++c) p[c] = 0.f;
            }
            // ---- D running window (ring idx u is compile-time) ----
#pragma unroll
            for (int c = 0; c < 5; ++c) {
                S[c] += p[c] - ring[c][u];
                ring[c][u] = p[c];
            }
            if (step >= 8 && step < 24) {            // emit out_d = d0 + step - 8
                const float cross = S[4] - S[0] * S[1] * WIN_INV;
                const float iv    = S[2] - S[0] * S[0] * WIN_INV;
                const float jv    = S[3] - S[1] * S[1] * WIN_INV;
                local += cross * cross / (iv * jv + 1e-5f);
            }
        }
    }
    block_reduce_atomic(local, red, &acc[0]);
}

// ---------------- MSE ----------------
__global__ __launch_bounds__(256) void mse_k(const float4* __restrict__ a,
                                             const float4* __restrict__ b,
                                             float* __restrict__ acc) {
    __shared__ float red[4];
    float local = 0.f;
    const int stride = gridDim.x * 256;
    for (int i = blockIdx.x * 256 + threadIdx.x; i < VOL / 4; i += stride) {
        const float4 x = a[i], y = b[i];
        const float d0 = x.x - y.x, d1 = x.y - y.y, d2 = x.z - y.z, d3 = x.w - y.w;
        local += d0 * d0 + d1 * d1 + d2 * d2 + d3 * d3;
    }
    block_reduce_atomic(local, red, &acc[1]);
}

// ---------------- smoothness ----------------
__global__ __launch_bounds__(256) void smooth_k(const float* __restrict__ s,
                                                float* __restrict__ acc) {
    __shared__ float red[4];
    float local = 0.f;
    const int stride = gridDim.x * 256;
    for (int i = blockIdx.x * 256 + threadIdx.x; i < FLOWN; i += stride) {
        const int w = i & 127, h = (i >> 7) & 127, d = (i >> 14) & 127;
        const float v = s[i];
        if (w < 127) { const float t = s[i + 1]     - v; local += t * t; }
        if (h < 127) { const float t = s[i + 128]   - v; local += t * t; }
        if (d < 127) { const float t = s[i + 16384] - v; local += t * t; }
    }
    block_reduce_atomic(local, red, &acc[2]);
}

// ---------------- finalize ----------------
__global__ void fin_k(const float* __restrict__ acc, float* __restrict__ out) {
    if (threadIdx.x == 0) {
        out[0] = 1.0f - acc[0] * (1.0f / (float)VOL);
        out[1] = acc[1] * (1.0f / (float)VOL);
        out[2] = acc[2] * (1.0f / (3.0f * SMCNT));
    }
}

extern "C" void kernel_launch(void* const* d_in, const int* in_sizes, int n_in,
                              void* d_out, int out_size, void* d_ws, size_t ws_size,
                              hipStream_t stream) {
    const float* imgsA  = (const float*)d_in[0];
    const float* recon  = (const float*)d_in[1];
    const float* warped = (const float*)d_in[2];
    const float* flow   = (const float*)d_in[3];
    float* out = (float*)d_out;
    float* acc = (float*)d_ws;

    hipMemsetAsync(d_ws, 0, 16, stream);

    ncc_k<<<1024, 256, 0, stream>>>(warped, imgsA, acc);   // I=warped, J=imgsA
    mse_k<<<1024, 256, 0, stream>>>((const float4*)imgsA, (const float4*)recon, acc);
    smooth_k<<<2048, 256, 0, stream>>>(flow, acc);
    fin_k<<<1, 64, 0, stream>>>(acc, out);
}

// Round 4
// 86.398 us; speedup vs baseline: 2.6967x; 1.5544x over previous
//
#include <hip/hip_runtime.h>

// Geometry (fixed): imgs [2,1,128,128,128] f32, flow [2,3,128,128,128] f32
#define VOL   4194304
#define FLOWN 12582912
#define SMCNT 12484608.0f   // 2*3*127*128*128
#define WIN_INV (1.0f / 729.0f)

__device__ __forceinline__ void block_reduce_atomic(float v, float* red, float* dst) {
#pragma unroll
    for (int off = 32; off; off >>= 1) v += __shfl_down(v, off);
    if ((threadIdx.x & 63) == 0) red[threadIdx.x >> 6] = v;
    __syncthreads();
    if (threadIdx.x == 0) atomicAdd(dst, red[0] + red[1] + red[2] + red[3]);
}

struct NccLds {
    float4 shI[24][6];      // I halo plane, 24x24 floats
    float4 shJ[24][6];      // J halo plane
    float  wst[5][16][28];  // W-sums, transposed [c][w][rr], rr padded 24->28
    float  hst[5][16][16];  // H-sums, [c][w][h]
};

union FusedLds {
    NccLds n;
    float dummy;
};

// ---- sliding 9-window over 12 inputs -> 4 outputs, write transposed ----
#define SLIDE(c, X0,X1,X2,X3,X4,X5,X6,X7,X8,X9,X10,X11)                    \
    {                                                                      \
        const float o0 = X0+X1+X2+X3+X4+X5+X6+X7+X8;                       \
        const float o1 = o0 - X0 + X9;                                     \
        const float o2 = o1 - X1 + X10;                                    \
        const float o3 = o2 - X2 + X11;                                    \
        L->n.wst[c][q4 + 0][rr] = o0;                                      \
        L->n.wst[c][q4 + 1][rr] = o1;                                      \
        L->n.wst[c][q4 + 2][rr] = o2;                                      \
        L->n.wst[c][q4 + 3][rr] = o3;                                      \
    }

__device__ void ncc_block(const float* __restrict__ I, const float* __restrict__ J,
                          float* __restrict__ acc, FusedLds* L, float* red, int nb) {
    const int wt = nb & 7, ht = (nb >> 3) & 7, dc = (nb >> 6) & 7, n = nb >> 9;
    const int w0 = wt << 4, h0 = ht << 4, d0 = dc << 4;
    const int tid = threadIdx.x;
    const int th = tid & 15;        // owned h
    const int tw = tid >> 4;        // owned w

    float ring[5][9];
#pragma unroll
    for (int c = 0; c < 5; ++c)
#pragma unroll
        for (int u = 0; u < 9; ++u) ring[c][u] = 0.f;
    float S[5] = {0.f, 0.f, 0.f, 0.f, 0.f};
    float local = 0.f;

    const long nbase = (long)n * 2097152;

    for (int s9 = 0; s9 < 27; s9 += 9) {
#pragma unroll
        for (int u = 0; u < 9; ++u) {
            const int step = s9 + u;
            const int dp = d0 - 4 + step;
            float p[5];
            const bool valid = (step < 24) && (dp >= 0) && (dp < 128);
            if (valid) {                               // block-uniform branch
                const long dbase = nbase + (long)dp * 16384;
                // ---- stage: 24 rows x 6 float4 (halo==4 -> OOB is whole-vector) ----
                if (tid < 144) {
                    const int rr = tid / 6, vq = tid - rr * 6;
                    const int gh = h0 - 4 + rr;
                    const int gw = w0 - 4 + 4 * vq;
                    float4 a = make_float4(0.f, 0.f, 0.f, 0.f), b = a;
                    if ((unsigned)gh < 128u && (unsigned)gw < 128u) {
                        const long idx = dbase + gh * 128 + gw;
                        a = *(const float4*)(I + idx);
                        b = *(const float4*)(J + idx);
                    }
                    L->n.shI[rr][vq] = a;
                    L->n.shJ[rr][vq] = b;
                }
                __syncthreads();
                // ---- W-pass: sliding along w, 5 channels, write transposed ----
                if (tid < 96) {
                    const int rr = tid >> 2, q = tid & 3, q4 = q << 2;
                    const float4 i0 = L->n.shI[rr][q];
                    const float4 i1 = L->n.shI[rr][q + 1];
                    const float4 i2 = L->n.shI[rr][q + 2];
                    const float4 j0 = L->n.shJ[rr][q];
                    const float4 j1 = L->n.shJ[rr][q + 1];
                    const float4 j2 = L->n.shJ[rr][q + 2];
                    SLIDE(0, i0.x,i0.y,i0.z,i0.w, i1.x,i1.y,i1.z,i1.w, i2.x,i2.y,i2.z,i2.w)
                    SLIDE(1, j0.x,j0.y,j0.z,j0.w, j1.x,j1.y,j1.z,j1.w, j2.x,j2.y,j2.z,j2.w)
                    SLIDE(2, i0.x*i0.x,i0.y*i0.y,i0.z*i0.z,i0.w*i0.w,
                             i1.x*i1.x,i1.y*i1.y,i1.z*i1.z,i1.w*i1.w,
                             i2.x*i2.x,i2.y*i2.y,i2.z*i2.z,i2.w*i2.w)
                    SLIDE(3, j0.x*j0.x,j0.y*j0.y,j0.z*j0.z,j0.w*j0.w,
                             j1.x*j1.x,j1.y*j1.y,j1.z*j1.z,j1.w*j1.w,
                             j2.x*j2.x,j2.y*j2.y,j2.z*j2.z,j2.w*j2.w)
                    SLIDE(4, i0.x*j0.x,i0.y*j0.y,i0.z*j0.z,i0.w*j0.w,
                             i1.x*j1.x,i1.y*j1.y,i1.z*j1.z,i1.w*j1.w,
                             i2.x*j2.x,i2.y*j2.y,i2.z*j2.z,i2.w*j2.w)
                }
                __syncthreads();
                // ---- H-pass: sliding along h (reads contiguous rr), b128 both ways ----
                {
                    const int c = tid >> 6, w = (tid >> 2) & 15, qh = tid & 3;
                    const float* sp = &L->n.wst[c][w][qh << 2];
                    const float4 a0 = *(const float4*)sp;
                    const float4 a1 = *(const float4*)(sp + 4);
                    const float4 a2 = *(const float4*)(sp + 8);
                    const float o0 = a0.x+a0.y+a0.z+a0.w+a1.x+a1.y+a1.z+a1.w+a2.x;
                    const float o1 = o0 - a0.x + a2.y;
                    const float o2 = o1 - a0.y + a2.z;
                    const float o3 = o2 - a0.z + a2.w;
                    *(float4*)&L->n.hst[c][w][qh << 2] = make_float4(o0, o1, o2, o3);
                }
                if (tid >= 192) {      // items 256..319 (c==4) on the lightest wave
                    const int i = tid + 64;
                    const int c = i >> 6, w = (i >> 2) & 15, qh = i & 3;
                    const float* sp = &L->n.wst[c][w][qh << 2];
                    const float4 a0 = *(const float4*)sp;
                    const float4 a1 = *(const float4*)(sp + 4);
                    const float4 a2 = *(const float4*)(sp + 8);
                    const float o0 = a0.x+a0.y+a0.z+a0.w+a1.x+a1.y+a1.z+a1.w+a2.x;
                    const float o1 = o0 - a0.x + a2.y;
                    const float o2 = o1 - a0.y + a2.z;
                    const float o3 = o2 - a0.z + a2.w;
                    *(float4*)&L->n.hst[c][w][qh << 2] = make_float4(o0, o1, o2, o3);
                }
                __syncthreads();
#pragma unroll
                for (int c = 0; c < 5; ++c) p[c] = L->n.hst[c][tw][th];
                // (no barrier needed: hst rewritten only after next plane's 2nd barrier)
            } else {
#pragma unroll
                for (int c = 0; c < 5; ++c) p[c] = 0.f;
            }
#pragma unroll
            for (int c = 0; c < 5; ++c) {
                S[c] += p[c] - ring[c][u];
                ring[c][u] = p[c];
            }
            if (step >= 8 && step < 24) {
                const float cross = S[4] - S[0] * S[1] * WIN_INV;
                const float iv    = S[2] - S[0] * S[0] * WIN_INV;
                const float jv    = S[3] - S[1] * S[1] * WIN_INV;
                local += cross * cross / (iv * jv + 1e-5f);
            }
        }
    }
    block_reduce_atomic(local, red, &acc[0]);
}

__device__ void mse_block(const float4* __restrict__ a, const float4* __restrict__ b,
                          float* __restrict__ acc, float* red, int mb) {
    float local = 0.f;
    for (int i = mb * 256 + threadIdx.x; i < VOL / 4; i += 512 * 256) {
        const float4 x = a[i], y = b[i];
        const float d0 = x.x - y.x, d1 = x.y - y.y, d2 = x.z - y.z, d3 = x.w - y.w;
        local += d0 * d0 + d1 * d1 + d2 * d2 + d3 * d3;
    }
    block_reduce_atomic(local, red, &acc[1]);
}

__device__ void smooth_block(const float4* __restrict__ s,
                             float* __restrict__ acc, float* red, int sb) {
    float local = 0.f;
    for (int f = sb * 256 + threadIdx.x; f < FLOWN / 4; f += 2048 * 256) {
        const int w4 = f & 31, h = (f >> 5) & 127, d = (f >> 12) & 127;
        const float4 v = s[f];
        const float t1 = v.y - v.x, t2 = v.z - v.y, t3 = v.w - v.z;
        local += t1 * t1 + t2 * t2 + t3 * t3;
        if (w4 < 31) {
            const float nx = ((const float*)s)[4 * f + 4];
            const float t = nx - v.w;
            local += t * t;
        }
        if (h < 127) {
            const float4 nh = s[f + 32];
            const float u0 = nh.x - v.x, u1 = nh.y - v.y, u2 = nh.z - v.z, u3 = nh.w - v.w;
            local += u0 * u0 + u1 * u1 + u2 * u2 + u3 * u3;
        }
        if (d < 127) {
            const float4 nd = s[f + 4096];
            const float u0 = nd.x - v.x, u1 = nd.y - v.y, u2 = nd.z - v.z, u3 = nd.w - v.w;
            local += u0 * u0 + u1 * u1 + u2 * u2 + u3 * u3;
        }
    }
    block_reduce_atomic(local, red, &acc[2]);
}

// Fused: 3584 blocks; g%7<2 -> ncc (1024), else mse (512) / smooth (2048).
// Interleaving keeps HBM-bound reduction blocks co-resident with the
// LDS/VALU-bound ncc blocks on each CU.
__global__ __launch_bounds__(256) void fused_k(const float* __restrict__ imgsA,
                                               const float* __restrict__ recon,
                                               const float* __restrict__ warped,
                                               const float* __restrict__ flow,
                                               float* __restrict__ acc) {
    __shared__ FusedLds L;
    __shared__ float red[4];
    const int g = blockIdx.x;
    const int r7 = g % 7, q7 = g / 7;
    if (r7 < 2) {
        ncc_block(warped, imgsA, acc, &L, red, q7 * 2 + r7);
    } else {
        const int mb = q7 * 5 + (r7 - 2);
        if (mb < 512) mse_block((const float4*)imgsA, (const float4*)recon, acc, red, mb);
        else          smooth_block((const float4*)flow, acc, red, mb - 512);
    }
}

__global__ void fin_k(const float* __restrict__ acc, float* __restrict__ out) {
    if (threadIdx.x == 0) {
        out[0] = 1.0f - acc[0] * (1.0f / (float)VOL);
        out[1] = acc[1] * (1.0f / (float)VOL);
        out[2] = acc[2] * (1.0f / (3.0f * SMCNT));
    }
}

extern "C" void kernel_launch(void* const* d_in, const int* in_sizes, int n_in,
                              void* d_out, int out_size, void* d_ws, size_t ws_size,
                              hipStream_t stream) {
    const float* imgsA  = (const float*)d_in[0];
    const float* recon  = (const float*)d_in[1];
    const float* warped = (const float*)d_in[2];
    const float* flow   = (const float*)d_in[3];
    float* out = (float*)d_out;
    float* acc = (float*)d_ws;

    hipMemsetAsync(d_ws, 0, 16, stream);
    fused_k<<<3584, 256, 0, stream>>>(imgsA, recon, warped, flow, acc);
    fin_k<<<1, 64, 0, stream>>>(acc, out);
}

// Round 5
// 81.995 us; speedup vs baseline: 2.8415x; 1.0537x over previous
//
#include <hip/hip_runtime.h>

// Geometry (fixed): imgs [2,1,128,128,128] f32, flow [2,3,128,128,128] f32
#define VOL   4194304
#define FLOWN 12582912
#define SMCNT 12484608.0f   // 2*3*127*128*128
#define WIN_INV (1.0f / 729.0f)

__device__ __forceinline__ void block_reduce_atomic(float v, float* red, float* dst) {
#pragma unroll
    for (int off = 32; off; off >>= 1) v += __shfl_down(v, off);
    if ((threadIdx.x & 63) == 0) red[threadIdx.x >> 6] = v;
    __syncthreads();
    if (threadIdx.x == 0) atomicAdd(dst, red[0] + red[1] + red[2] + red[3]);
}

struct __align__(16) NccLds {
    float wst[2][5][16][28];  // [plane][chan][w][rr] W-sums transposed, rr 24->28 pad
    float hst[2][5][16][16];  // [plane][chan][w][h]  H-sums
};

// sliding 9-window over 12 inputs -> 4 outputs, transposed write at row wrr
#define WSLIDE(c, X0,X1,X2,X3,X4,X5,X6,X7,X8,X9,X10,X11)                   \
    {                                                                      \
        const float o0 = X0+X1+X2+X3+X4+X5+X6+X7+X8;                       \
        const float o1 = o0 - X0 + X9;                                     \
        const float o2 = o1 - X1 + X10;                                    \
        const float o3 = o2 - X2 + X11;                                    \
        L->wst[wpl][c][wq4 + 0][wrr] = o0;                                 \
        L->wst[wpl][c][wq4 + 1][wrr] = o1;                                 \
        L->wst[wpl][c][wq4 + 2][wrr] = o2;                                 \
        L->wst[wpl][c][wq4 + 3][wrr] = o3;                                 \
    }

// Block = (n, h-tile 16, w-tile 16, d-chunk 16); marches 24 d-planes in 12
// pairs; 1 barrier per plane. No LDS staging of I/J: W-pass reads the halo
// directly from global (inputs are L2/L3-resident).
__device__ void ncc_block(const float* __restrict__ I, const float* __restrict__ J,
                          float* __restrict__ acc, NccLds* L, float* red, int nb) {
    const int wt = nb & 7, ht = (nb >> 3) & 7, dc = (nb >> 6) & 7, n = nb >> 9;
    const int w0 = wt << 4, h0 = ht << 4, d0 = dc << 4;
    const int tid = threadIdx.x;
    const int th = tid & 15;        // owned h
    const int tw = tid >> 4;        // owned w

    // W-phase decomposition: threads 0..191 -> (plane, rr 0..23, q 0..3)
    const int wpl = tid / 96;
    const int wit = tid - wpl * 96;
    const int wrr = wit >> 2;
    const int wq4 = (wit & 3) << 2;
    const int gh  = h0 - 4 + wrr;
    const int gwb = w0 + wq4 - 4;   // first of 3 aligned float4 columns

    float hist[5][9];               // hist[c][k] = p at step (s-1-k), static idx only
#pragma unroll
    for (int c = 0; c < 5; ++c)
#pragma unroll
        for (int k = 0; k < 9; ++k) hist[c][k] = 0.f;
    float S[5] = {0.f, 0.f, 0.f, 0.f, 0.f};
    float local = 0.f;
    const long nbase = (long)n * 2097152;

    for (int pp = 0; pp < 12; ++pp) {
        // ---- W phase: global(L2) -> regs -> wst (transposed) ----
        {
            const int s  = 2 * pp + wpl;
            const int dp = d0 - 4 + s;
            if (tid < 192 && (unsigned)dp < 128u) {
                const float4 z4 = make_float4(0.f, 0.f, 0.f, 0.f);
                float4 i0 = z4, i1 = z4, i2 = z4, j0 = z4, j1 = z4, j2 = z4;
                if ((unsigned)gh < 128u) {
                    const float* Ip = I + nbase + (long)dp * 16384 + gh * 128 + gwb;
                    const float* Jp = J + nbase + (long)dp * 16384 + gh * 128 + gwb;
                    if (gwb >= 0)   { i0 = *(const float4*)Ip;       j0 = *(const float4*)Jp; }
                    i1 = *(const float4*)(Ip + 4);                   j1 = *(const float4*)(Jp + 4);
                    if (gwb <= 116) { i2 = *(const float4*)(Ip + 8); j2 = *(const float4*)(Jp + 8); }
                }
                WSLIDE(0, i0.x,i0.y,i0.z,i0.w, i1.x,i1.y,i1.z,i1.w, i2.x,i2.y,i2.z,i2.w)
                WSLIDE(1, j0.x,j0.y,j0.z,j0.w, j1.x,j1.y,j1.z,j1.w, j2.x,j2.y,j2.z,j2.w)
                WSLIDE(2, i0.x*i0.x,i0.y*i0.y,i0.z*i0.z,i0.w*i0.w,
                          i1.x*i1.x,i1.y*i1.y,i1.z*i1.z,i1.w*i1.w,
                          i2.x*i2.x,i2.y*i2.y,i2.z*i2.z,i2.w*i2.w)
                WSLIDE(3, j0.x*j0.x,j0.y*j0.y,j0.z*j0.z,j0.w*j0.w,
                          j1.x*j1.x,j1.y*j1.y,j1.z*j1.z,j1.w*j1.w,
                          j2.x*j2.x,j2.y*j2.y,j2.z*j2.z,j2.w*j2.w)
                WSLIDE(4, i0.x*j0.x,i0.y*j0.y,i0.z*j0.z,i0.w*j0.w,
                          i1.x*j1.x,i1.y*j1.y,i1.z*j1.z,i1.w*j1.w,
                          i2.x*j2.x,i2.y*j2.y,i2.z*j2.z,i2.w*j2.w)
            }
        }
        __syncthreads();
        // ---- H phase: 640 items = (plane, c, w, qh); sliding along rr ----
#pragma unroll
        for (int rep = 0; rep < 3; ++rep) {
            int id = -1;
            if (rep < 2) id = tid + rep * 256;
            else if (tid >= 128) id = 384 + tid;      // waves 2,3 take the tail
            if (id >= 0 && id < 640) {
                const int pl = id >= 320;
                const int r2 = id - pl * 320;
                const int c  = r2 >> 6;
                const int w  = (r2 >> 2) & 15;
                const int qh = r2 & 3;
                const int dp = d0 - 4 + 2 * pp + pl;
                if ((unsigned)dp < 128u) {
                    const float* sp = &L->wst[pl][c][w][qh << 2];
                    const float4 a0 = *(const float4*)sp;
                    const float4 a1 = *(const float4*)(sp + 4);
                    const float4 a2 = *(const float4*)(sp + 8);
                    const float o0 = a0.x+a0.y+a0.z+a0.w+a1.x+a1.y+a1.z+a1.w+a2.x;
                    const float o1 = o0 - a0.x + a2.y;
                    const float o2 = o1 - a0.y + a2.z;
                    const float o3 = o2 - a0.z + a2.w;
                    *(float4*)&L->hst[pl][c][w][qh << 2] = make_float4(o0, o1, o2, o3);
                }
            }
        }
        __syncthreads();
        // ---- final: D running window for both planes (static hist indices) ----
        {
            const int dp0 = d0 - 4 + 2 * pp;
            float p0[5], p1[5];
            if ((unsigned)dp0 < 128u) {
#pragma unroll
                for (int c = 0; c < 5; ++c) p0[c] = L->hst[0][c][tw][th];
            } else {
#pragma unroll
                for (int c = 0; c < 5; ++c) p0[c] = 0.f;
            }
            if ((unsigned)(dp0 + 1) < 128u) {
#pragma unroll
                for (int c = 0; c < 5; ++c) p1[c] = L->hst[1][c][tw][th];
            } else {
#pragma unroll
                for (int c = 0; c < 5; ++c) p1[c] = 0.f;
            }
#pragma unroll
            for (int c = 0; c < 5; ++c) S[c] += p0[c] - hist[c][8];
            if (pp >= 4) {
                const float cross = S[4] - S[0] * S[1] * WIN_INV;
                const float iv    = S[2] - S[0] * S[0] * WIN_INV;
                const float jv    = S[3] - S[1] * S[1] * WIN_INV;
                local += cross * cross / (iv * jv + 1e-5f);
            }
#pragma unroll
            for (int c = 0; c < 5; ++c) S[c] += p1[c] - hist[c][7];
            if (pp >= 4) {
                const float cross = S[4] - S[0] * S[1] * WIN_INV;
                const float iv    = S[2] - S[0] * S[0] * WIN_INV;
                const float jv    = S[3] - S[1] * S[1] * WIN_INV;
                local += cross * cross / (iv * jv + 1e-5f);
            }
#pragma unroll
            for (int c = 0; c < 5; ++c) {
#pragma unroll
                for (int k = 8; k >= 2; --k) hist[c][k] = hist[c][k - 2];
                hist[c][1] = p0[c];
                hist[c][0] = p1[c];
            }
        }
    }
    block_reduce_atomic(local, red, &acc[0]);
}

__device__ void mse_block(const float4* __restrict__ a, const float4* __restrict__ b,
                          float* __restrict__ acc, float* red, int mb) {
    float local = 0.f;
    for (int i = mb * 256 + threadIdx.x; i < VOL / 4; i += 512 * 256) {
        const float4 x = a[i], y = b[i];
        const float d0 = x.x - y.x, d1 = x.y - y.y, d2 = x.z - y.z, d3 = x.w - y.w;
        local += d0 * d0 + d1 * d1 + d2 * d2 + d3 * d3;
    }
    block_reduce_atomic(local, red, &acc[1]);
}

__device__ void smooth_block(const float4* __restrict__ s,
                             float* __restrict__ acc, float* red, int sb) {
    float local = 0.f;
    for (int f = sb * 256 + threadIdx.x; f < FLOWN / 4; f += 2048 * 256) {
        const int w4 = f & 31, h = (f >> 5) & 127, d = (f >> 12) & 127;
        const float4 v = s[f];
        const float t1 = v.y - v.x, t2 = v.z - v.y, t3 = v.w - v.z;
        local += t1 * t1 + t2 * t2 + t3 * t3;
        if (w4 < 31) {
            const float nx = ((const float*)s)[4 * f + 4];
            const float t = nx - v.w;
            local += t * t;
        }
        if (h < 127) {
            const float4 nh = s[f + 32];
            const float u0 = nh.x - v.x, u1 = nh.y - v.y, u2 = nh.z - v.z, u3 = nh.w - v.w;
            local += u0 * u0 + u1 * u1 + u2 * u2 + u3 * u3;
        }
        if (d < 127) {
            const float4 nd = s[f + 4096];
            const float u0 = nd.x - v.x, u1 = nd.y - v.y, u2 = nd.z - v.z, u3 = nd.w - v.w;
            local += u0 * u0 + u1 * u1 + u2 * u2 + u3 * u3;
        }
    }
    block_reduce_atomic(local, red, &acc[2]);
}

// ncc blocks FIRST (g<1024) so every CU gets its long-pole blocks at t=0;
// mse (512) / smooth (2048) backfill and drain HBM concurrently.
__global__ __launch_bounds__(256) void fused_k(const float* __restrict__ imgsA,
                                               const float* __restrict__ recon,
                                               const float* __restrict__ warped,
                                               const float* __restrict__ flow,
                                               float* __restrict__ acc) {
    __shared__ NccLds Lsh;
    __shared__ float red[4];
    const int g = blockIdx.x;
    if (g < 1024) {
        ncc_block(warped, imgsA, acc, &Lsh, red, g);
    } else {
        const int x = g - 1024;
        const int q = x / 5, r = x - q * 5;
        if (r == 0) mse_block((const float4*)imgsA, (const float4*)recon, acc, red, q);
        else        smooth_block((const float4*)flow, acc, red, q * 4 + (r - 1));
    }
}

__global__ void fin_k(const float* __restrict__ acc, float* __restrict__ out) {
    if (threadIdx.x == 0) {
        out[0] = 1.0f - acc[0] * (1.0f / (float)VOL);
        out[1] = acc[1] * (1.0f / (float)VOL);
        out[2] = acc[2] * (1.0f / (3.0f * SMCNT));
    }
}

extern "C" void kernel_launch(void* const* d_in, const int* in_sizes, int n_in,
                              void* d_out, int out_size, void* d_ws, size_t ws_size,
                              hipStream_t stream) {
    const float* imgsA  = (const float*)d_in[0];
    const float* recon  = (const float*)d_in[1];
    const float* warped = (const float*)d_in[2];
    const float* flow   = (const float*)d_in[3];
    float* out = (float*)d_out;
    float* acc = (float*)d_ws;

    hipMemsetAsync(d_ws, 0, 16, stream);
    fused_k<<<3584, 256, 0, stream>>>(imgsA, recon, warped, flow, acc);
    fin_k<<<1, 64, 0, stream>>>(acc, out);
}